// Round 15
// baseline (126.350 us; speedup 1.0000x reference)
//
#include <hip/hip_runtime.h>

#define N2 4096
#define D 128
#define TAU_INV 10.0f
#define E2SCALE 14.4269504088896340736f   // 10 * log2(e): exp(10x) = exp2(x*E2SCALE)
#define BM 256                    // i-rows per block (8 waves x 32)
#define BN 256                    // j-cols per block (8 tiles, LDS-staged)
#define NT (BN / 32)              // 8
#define NIT (N2 / BM)             // 16
#define GEMM_BLOCKS (NIT * NIT)   // 256 = exactly one per CU, ONE scheduling round
#define NCLS 10
#define PCB 1300                  // per-diagonal-block class partial: S[10][128],T[10],CNT[10]

typedef __attribute__((ext_vector_type(8))) short bf16x8;
typedef __attribute__((ext_vector_type(16))) float floatx16;

__device__ __forceinline__ short f2bf(float f) {
    unsigned u = __float_as_uint(f);
    u = (u + 0x7fff + ((u >> 16) & 1)) >> 16;   // RNE
    return (short)u;
}
__device__ __forceinline__ float bf2f(short s) {
    return __uint_as_float(((unsigned)(unsigned short)s) << 16);
}

// ONE kernel, 256 blocks (one per CU, single scheduling round — r14's extra
// 160 class blocks ran as a serialized second round; that round is gone).
// Block (it,js): normalizes B-range rows js*256..+256 from zi/zj into 64KB
// LDS chunk-major (bf16 q values), A-range per-wave into registers, runs the
// K-loop (MFMA 32x32x16, K=128, B via ds_read), plain-stores per-row 256-col
// exp-sum partials to pse[row][js]. The 16 DIAGONAL blocks (it==js) then
// re-read their own ldsB — which holds exactly the q values of rows
// js*256..+256 — and accumulate the class partials (S_c/T_c/CNT_c) via LDS
// scatter-adds, storing one 1300-float partial. No atomics to global, nothing
// zero-initialized, labels used as values only (guarded where indexed).
// C/D: col=lane&31, row=(reg&3)+8*(reg>>2)+4*(lane>>5); diagonal tile
// (j0==rbase) wave-uniform; self-pair excluded exactly as all prior rounds.
__global__ __launch_bounds__(512) void main_kernel(const float* __restrict__ zi,
                                                   const float* __restrict__ zj,
                                                   const long long* __restrict__ y,
                                                   float* __restrict__ pse,
                                                   float* __restrict__ pcls) {
    __shared__ short ldsB[BN * D];          // 64 KB
    __shared__ float shF[PCB + 12];         // class partial accumulator (5.2 KB)
    int tid = threadIdx.x;
    int wave = tid >> 6;
    int lane = tid & 63;
    int gb = blockIdx.x;
    int col  = lane & 31;
    int half = lane >> 5;
    int it = gb >> 4;                  // 0..15
    int js = gb & 15;                  // 0..15
    int rbase = it * BM + wave * 32;

    // stage B-range into LDS chunk-major: 2 passes x (128 rows, 4 threads/row)
    #pragma unroll
    for (int pass = 0; pass < 2; ++pass) {
        int rl = pass * 128 + (tid >> 2);           // 0..255 row within range
        int q  = tid & 3;                           // dim quarter: d0 = q*32
        int gr = js * BN + rl;
        const float* srcb = (gr < 2048) ? (zi + gr * D) : (zj + (gr - 2048) * D);
        float4 b0[8];
        float part = 0.f;
        #pragma unroll
        for (int j = 0; j < 8; ++j) {
            float4 u = *(const float4*)(srcb + q * 32 + j * 4);
            part += u.x * u.x + u.y * u.y + u.z * u.z + u.w * u.w;
            b0[j] = u;
        }
        part += __shfl_xor(part, 1);
        part += __shfl_xor(part, 2);                // quad sum = full-row ssq
        float invb = 1.0f / sqrtf(part);
        #pragma unroll
        for (int jj = 0; jj < 4; ++jj) {
            float4 u = b0[2 * jj], v = b0[2 * jj + 1];
            bf16x8 t;
            t[0] = f2bf(u.x * invb); t[1] = f2bf(u.y * invb);
            t[2] = f2bf(u.z * invb); t[3] = f2bf(u.w * invb);
            t[4] = f2bf(v.x * invb); t[5] = f2bf(v.y * invb);
            t[6] = f2bf(v.z * invb); t[7] = f2bf(v.w * invb);
            *(bf16x8*)&ldsB[(rl >> 5) * 4096 + (q * 4 + jj) * 256 + (rl & 31) * 8] = t;
        }
    }

    // A fragments in registers: lane owns dims {k*16+half*8..+8} of row rbase+col
    bf16x8 af[8];
    {
        int grow = rbase + col;
        const float* srca = (grow < 2048) ? (zi + grow * D) : (zj + (grow - 2048) * D);
        float4 a0[8], a1[8];
        float ssq = 0.f;
        #pragma unroll
        for (int k = 0; k < 8; ++k) {
            float4 u = *(const float4*)(srca + k * 16 + half * 8);
            float4 v = *(const float4*)(srca + k * 16 + half * 8 + 4);
            ssq += u.x * u.x + u.y * u.y + u.z * u.z + u.w * u.w
                 + v.x * v.x + v.y * v.y + v.z * v.z + v.w * v.w;
            a0[k] = u; a1[k] = v;
        }
        ssq += __shfl_xor(ssq, 32);                 // other half-lane: same row
        float inv = 1.0f / sqrtf(ssq);
        #pragma unroll
        for (int k = 0; k < 8; ++k) {
            bf16x8 t;
            t[0] = f2bf(a0[k].x * inv); t[1] = f2bf(a0[k].y * inv);
            t[2] = f2bf(a0[k].z * inv); t[3] = f2bf(a0[k].w * inv);
            t[4] = f2bf(a1[k].x * inv); t[5] = f2bf(a1[k].y * inv);
            t[6] = f2bf(a1[k].z * inv); t[7] = f2bf(a1[k].w * inv);
            af[k] = t;
        }
    }

    float se[16];
    #pragma unroll
    for (int r = 0; r < 16; ++r) se[r] = 0.f;

    __syncthreads();                   // B staged

    const bf16x8* lb = (const bf16x8*)ldsB;
    #pragma unroll
    for (int t = 0; t < NT; ++t) {
        int j0 = js * BN + t * 32;

        floatx16 acc;
        #pragma unroll
        for (int r = 0; r < 16; ++r) acc[r] = 0.f;
        #pragma unroll
        for (int k = 0; k < 8; ++k)
            acc = __builtin_amdgcn_mfma_f32_32x32x16_bf16(
                af[k], lb[t * 512 + k * 64 + lane], acc, 0, 0, 0);

        if (j0 == rbase) {                    // wave-uniform: diagonal tile
            int jcol = j0 + col;
            #pragma unroll
            for (int r = 0; r < 16; ++r) {
                int rowr = rbase + (r & 3) + 8 * (r >> 2) + 4 * half;
                float e = __builtin_amdgcn_exp2f(acc[r] * E2SCALE);
                se[r] += (rowr == jcol) ? 0.f : e;
            }
        } else {
            #pragma unroll
            for (int r = 0; r < 16; ++r)
                se[r] += __builtin_amdgcn_exp2f(acc[r] * E2SCALE);
        }
    }

    // reduce over 32 cols; PLAIN STORE this block's 256-col partial per row
    #pragma unroll
    for (int r = 0; r < 16; ++r) {
        float a = se[r];
        #pragma unroll
        for (int m = 1; m < 32; m <<= 1) a += __shfl_xor(a, m);
        if (col == 0) {
            int rowr = rbase + (r & 3) + 8 * (r >> 2) + 4 * half;
            pse[rowr * NIT + js] = a;         // unique (row, js) writer
        }
    }

    // ---- class partials: only the 16 diagonal blocks, from their own ldsB ----
    if (it == js) {
        for (int k = tid; k < PCB; k += 512) shF[k] = 0.f;
        __syncthreads();
        // 256 rows x 128 dims; 32 threads per row, 4 dims per thread, 16 passes
        int d0 = 4 * (tid & 31);
        for (int i = 0; i < 16; ++i) {
            int rl = (tid >> 5) + 16 * i;                   // 0..255
            int c = (int)y[(js * BN + rl) & 2047];
            const short* p = &ldsB[(rl >> 5) * 4096 + (d0 >> 3) * 256 + (rl & 31) * 8 + (d0 & 7)];
            float q0 = bf2f(p[0]), q1 = bf2f(p[1]), q2 = bf2f(p[2]), q3 = bf2f(p[3]);
            bool ok = ((unsigned)c < (unsigned)NCLS);       // guard: no data-dep OOB
            if (ok) {
                atomicAdd(&shF[c * D + d0],     q0);
                atomicAdd(&shF[c * D + d0 + 1], q1);
                atomicAdd(&shF[c * D + d0 + 2], q2);
                atomicAdd(&shF[c * D + d0 + 3], q3);
            }
            float t4 = q0 * q0 + q1 * q1 + q2 * q2 + q3 * q3;
            #pragma unroll
            for (int m = 1; m < 32; m <<= 1) t4 += __shfl_xor(t4, m);
            if ((tid & 31) == 0 && ok) {
                atomicAdd(&shF[NCLS * D + c], t4);          // T_c
                atomicAdd(&shF[NCLS * D + NCLS + c], 1.f);  // CNT_c
            }
        }
        __syncthreads();
        for (int k = tid; k < PCB; k += 512) pcls[it * PCB + k] = shF[k];
    }
}

// loss = (sum_i log(sum_js pse[i][js])  -  sum_c 10*(||S_c||^2 - T_c)/(n_c-1)) / N2
__global__ __launch_bounds__(512) void finish_kernel(const float* __restrict__ pse,
                                                     const float* __restrict__ pcls,
                                                     float* __restrict__ out) {
    __shared__ float red[16];
    int tid = threadIdx.x;
    int wave = tid >> 6;
    int lane = tid & 63;

    // denominator: sum 16 j-partials per row (64B contiguous), log, reduce
    float L = 0.f;
    for (int r = tid; r < N2; r += 512) {
        float s = 0.f;
        #pragma unroll
        for (int js = 0; js < NIT; ++js) s += pse[r * NIT + js];
        L += __logf(s);
    }
    #pragma unroll
    for (int m = 1; m < 64; m <<= 1) L += __shfl_xor(L, m);

    // positive-pair term: wave w handles classes w and w+8
    float P = 0.f;
    for (int c = wave; c < NCLS; c += 8) {
        float Sx = 0.f, Sy = 0.f, T = 0.f, n = 0.f;
        #pragma unroll
        for (int b = 0; b < NIT; ++b) {
            const float* p = pcls + b * PCB;
            Sx += p[c * D + 2 * lane];
            Sy += p[c * D + 2 * lane + 1];
            T  += p[NCLS * D + c];
            n  += p[NCLS * D + NCLS + c];
        }
        float s2 = Sx * Sx + Sy * Sy;
        #pragma unroll
        for (int m = 1; m < 64; m <<= 1) s2 += __shfl_xor(s2, m);
        P += (n >= 2.0f) ? (s2 - T) * TAU_INV / (n - 1.0f) : 0.f;
    }

    if (lane == 0) { red[wave] = L; red[8 + wave] = P; }
    __syncthreads();
    if (tid == 0) {
        float Ls = 0.f, Ps = 0.f;
        #pragma unroll
        for (int w = 0; w < 8; ++w) { Ls += red[w]; Ps += red[8 + w]; }
        out[0] = (Ls - Ps) * (1.0f / (float)N2);
    }
}

extern "C" void kernel_launch(void* const* d_in, const int* in_sizes, int n_in,
                              void* d_out, int out_size, void* d_ws, size_t ws_size,
                              hipStream_t stream) {
    const float*     zi = (const float*)d_in[0];
    const float*     zj = (const float*)d_in[1];
    const long long* y  = (const long long*)d_in[2];
    float* out = (float*)d_out;

    char* ws = (char*)d_ws;
    float* pse  = (float*)ws;                      // 4096*16 f32 = 256 KB (no init needed)
    float* pcls = pse + N2 * NIT;                  // 16*1300 f32 = 83 KB (no init needed)

    main_kernel<<<GEMM_BLOCKS, 512, 0, stream>>>(zi, zj, y, pse, pcls);
    finish_kernel<<<1, 512, 0, stream>>>(pse, pcls, out);
}

// Round 16
// 83.851 us; speedup vs baseline: 1.5069x; 1.5069x over previous
//
#include <hip/hip_runtime.h>

#define N2 4096
#define D 128
#define TAU_INV 10.0f
#define E2SCALE 14.4269504088896340736f   // 10 * log2(e): exp(10x) = exp2(x*E2SCALE)
#define BM 256                    // i-rows per block (8 waves x 32)
#define BN 256                    // j-cols per block (8 tiles, LDS-staged)
#define NT (BN / 32)              // 8
#define NIT (N2 / BM)             // 16
#define GEMM_BLOCKS (NIT * (NIT + 1) / 2)   // 136: only tiles it <= js (symmetry!)
#define NCLS 10
#define CGRP 16
#define CROWS (N2 / CGRP)         // 256 rows per class block
#define CB (NCLS * CGRP)          // 160 class blocks

typedef __attribute__((ext_vector_type(8))) short bf16x8;
typedef __attribute__((ext_vector_type(16))) float floatx16;

__device__ __forceinline__ short f2bf(float f) {
    unsigned u = __float_as_uint(f);
    u = (u + 0x7fff + ((u >> 16) & 1)) >> 16;   // RNE
    return (short)u;
}
__device__ __forceinline__ float bf2f(short s) {
    return __uint_as_float(((unsigned)(unsigned short)s) << 16);
}

// Normalize rows of p = concat(z_i, z_j) in fp32, emit bf16. Two layouts:
//   qb  [row][d]                  row-major (class-sum path)
//   qb2 [row/32][k/8][row%32][8]  chunk-major (MFMA fragments + LDS staging)
// Block 0 zeroes S/T/CNT (class accumulators).
__global__ __launch_bounds__(64) void prep_kernel(const float* __restrict__ zi,
                                                  const float* __restrict__ zj,
                                                  short* __restrict__ qb,
                                                  short* __restrict__ qb2,
                                                  float* __restrict__ S) {
    int row = blockIdx.x;
    int lane = threadIdx.x;                    // 64 lanes, 2 floats each
    const float* src = (row < 2048) ? (zi + row * D) : (zj + (row - 2048) * D);
    float2 v = ((const float2*)src)[lane];
    float ss = v.x * v.x + v.y * v.y;
    #pragma unroll
    for (int m = 1; m < 64; m <<= 1) ss += __shfl_xor(ss, m);
    float inv = 1.0f / sqrtf(ss);              // ||p|| ~ sqrt(128) >> eps
    short2 o;
    o.x = f2bf(v.x * inv);
    o.y = f2bf(v.y * inv);
    ((short2*)(qb + row * D))[lane] = o;
    int addr2 = (row >> 5) * 4096 + (lane >> 2) * 256 + (row & 31) * 8 + 2 * (lane & 3);
    *(short2*)(qb2 + addr2) = o;
    if (row == 0)
        for (int k = lane; k < NCLS * D + 2 * NCLS; k += 64) S[k] = 0.f;
}

// Grid = 136 GEMM blocks (upper-triangle tiles, it<=js) + 160 class blocks.
//
// SYMMETRY: s_ij = s_ji, so block (it,js) computes its 256x256 tile ONCE and
// produces BOTH halves of the exp-sum: row-sums (reduce over cols) -> slice js
// of rows in it-block, AND (off-diag only) col-sums (reduce over rows) ->
// slice it of rows in js-block. Col-sum is cheap: lane sums its 16 acc regs
// in-register + shfl_xor(32) + cross-wave LDS accumulate. pse[row][slice] has
// exactly one writer per slot (k<J from block (k,J) col-sums; k>=J from block
// (J,k) row-sums) -> plain stores, no atomics, no zero-init. GEMM+exp work
// HALVES vs r13 (256 -> 136 tile-blocks).
// B-slice staged to LDS from qb2 (64KB contiguous); A per-wave in registers;
// MFMA 32x32x16, K=128. C/D: col=lane&31, row=(reg&3)+8*(reg>>2)+4*(lane>>5).
// Diagonal tile (j0==rbase, only when it==js) wave-uniform; self-pair excluded.
//
// Class block: masked S/T/CNT sums over 256 rows of qb (r13's proven path;
// labels used as VALUES only -> poison-safe).
__global__ __launch_bounds__(512) void main_kernel(const short* __restrict__ qb,
                                                   const short* __restrict__ qb2,
                                                   const long long* __restrict__ y,
                                                   float* __restrict__ pse,
                                                   float* __restrict__ S) {
    int tid = threadIdx.x;
    int wave = tid >> 6;
    int lane = tid & 63;

    if (blockIdx.x >= GEMM_BLOCKS) {
        // ---- class-sum path (512 threads: 4 row-groups x 128 dims) ----
        __shared__ float shS[512];
        __shared__ float shT[8];
        __shared__ float shC[4];
        int cb = blockIdx.x - GEMM_BLOCKS;   // 0..159
        int c  = cb / CGRP;
        int g  = cb % CGRP;
        int d  = tid & 127;
        int rg = tid >> 7;                   // 0..3
        int r0 = g * CROWS + rg * (CROWS / 4);

        float sS = 0.f, sT = 0.f, cnt = 0.f;
        #pragma unroll 4
        for (int i = 0; i < CROWS / 4; ++i) {
            int r = r0 + i;
            bool m = ((int)y[r & 2047] == c);      // wave-uniform broadcast
            float q = bf2f(qb[r * D + d]);         // coalesced reads
            sS += m ? q : 0.f;
            sT += m ? q * q : 0.f;
            cnt += m ? 1.f : 0.f;
        }

        shS[tid] = sS;
        #pragma unroll
        for (int m = 1; m < 64; m <<= 1) sT += __shfl_xor(sT, m);
        if (lane == 0) shT[wave] = sT;
        if (d == 0) shC[rg] = cnt;
        __syncthreads();
        if (tid < 128)
            atomicAdd(&S[c * D + tid],
                      shS[tid] + shS[tid + 128] + shS[tid + 256] + shS[tid + 384]);
        if (tid == 0) {
            float t8 = 0.f;
            #pragma unroll
            for (int w = 0; w < 8; ++w) t8 += shT[w];
            atomicAdd(&S[NCLS * D + c], t8);                                  // T_c
            atomicAdd(&S[NCLS * D + NCLS + c], shC[0] + shC[1] + shC[2] + shC[3]); // CNT_c
        }
        return;
    }

    // ---- GEMM path: map linear block id -> upper-triangle (it, js) ----
    __shared__ short ldsB[BN * D];     // 64 KB
    __shared__ float colsum[BN];       // 1 KB (off-diag col-sums)
    int b = blockIdx.x, it = 0;
    while (b >= NIT - it) { b -= NIT - it; ++it; }
    int js = it + b;
    int col  = lane & 31;
    int half = lane >> 5;
    int rbase = it * BM + wave * 32;
    bool offdiag = (it != js);

    // stage the B-slice: 64KB contiguous in qb2, coalesced copy
    {
        const bf16x8* src = (const bf16x8*)(qb2 + js * (BN * D));
        bf16x8* dst = (bf16x8*)ldsB;
        #pragma unroll
        for (int i = 0; i < 8; ++i) dst[tid + 512 * i] = src[tid + 512 * i];
    }
    if (tid < BN) colsum[tid] = 0.f;

    // A fragments for this wave's 32 rows: lane-contiguous from qb2
    const short* ap = qb2 + ((rbase >> 5) * 4096) + lane * 8;
    bf16x8 af[8];
    #pragma unroll
    for (int k = 0; k < 8; ++k) af[k] = *(const bf16x8*)(ap + k * 512);

    float se[16];
    #pragma unroll
    for (int r = 0; r < 16; ++r) se[r] = 0.f;

    __syncthreads();                   // B staged, colsum zeroed

    const bf16x8* lb = (const bf16x8*)ldsB;
    #pragma unroll
    for (int t = 0; t < NT; ++t) {
        int j0 = js * BN + t * 32;

        floatx16 acc;
        #pragma unroll
        for (int r = 0; r < 16; ++r) acc[r] = 0.f;
        #pragma unroll
        for (int k = 0; k < 8; ++k)
            acc = __builtin_amdgcn_mfma_f32_32x32x16_bf16(
                af[k], lb[t * 512 + k * 64 + lane], acc, 0, 0, 0);

        if (j0 == rbase) {                    // wave-uniform: diagonal tile
            int jcol = j0 + col;
            #pragma unroll
            for (int r = 0; r < 16; ++r) {
                int rowr = rbase + (r & 3) + 8 * (r >> 2) + 4 * half;
                float e = __builtin_amdgcn_exp2f(acc[r] * E2SCALE);
                se[r] += (rowr == jcol) ? 0.f : e;
            }
        } else {
            float cs = 0.f;
            #pragma unroll
            for (int r = 0; r < 16; ++r) {
                float e = __builtin_amdgcn_exp2f(acc[r] * E2SCALE);
                se[r] += e;
                cs += e;
            }
            if (offdiag) {                    // col-sums for the mirrored tile
                cs += __shfl_xor(cs, 32);     // both halves: full 32-row sum
                if (half == 0) atomicAdd(&colsum[t * 32 + col], cs);
            }
        }
    }

    // row-sums: reduce over 32 cols, plain-store slice js for it-block rows
    #pragma unroll
    for (int r = 0; r < 16; ++r) {
        float a = se[r];
        #pragma unroll
        for (int m = 1; m < 32; m <<= 1) a += __shfl_xor(a, m);
        if (col == 0) {
            int rowr = rbase + (r & 3) + 8 * (r >> 2) + 4 * half;
            pse[rowr * NIT + js] = a;         // unique (row, js) writer
        }
    }

    // col-sums: slice it for js-block rows (mirrored half), plain store
    if (offdiag) {
        __syncthreads();                      // all waves' colsum adds done
        if (tid < BN)
            pse[(js * BN + tid) * NIT + it] = colsum[tid];   // unique writer
    }
}

// loss = (sum_i log(sum_k pse[i][k])  -  sum_c 10*(||S_c||^2 - T_c)/(n_c-1)) / N2
__global__ __launch_bounds__(512) void finish_kernel(const float* __restrict__ pse,
                                                     const float* __restrict__ S,
                                                     float* __restrict__ out) {
    __shared__ float red[16];
    int tid = threadIdx.x;
    int wave = tid >> 6;
    int lane = tid & 63;

    // denominator: sum 16 slice-partials per row (64B contiguous), log, reduce
    float L = 0.f;
    for (int r = tid; r < N2; r += 512) {
        float s = 0.f;
        #pragma unroll
        for (int k = 0; k < NIT; ++k) s += pse[r * NIT + k];
        L += __logf(s);
    }
    #pragma unroll
    for (int m = 1; m < 64; m <<= 1) L += __shfl_xor(L, m);

    // positive-pair term: wave w handles classes w and w+8
    float P = 0.f;
    for (int c = wave; c < NCLS; c += 8) {
        float2 sv = ((const float2*)(S + c * D))[lane];
        float s2 = sv.x * sv.x + sv.y * sv.y;
        #pragma unroll
        for (int m = 1; m < 64; m <<= 1) s2 += __shfl_xor(s2, m);
        float n = S[NCLS * D + NCLS + c];
        P += (n >= 2.0f) ? (s2 - S[NCLS * D + c]) * TAU_INV / (n - 1.0f) : 0.f;
    }

    if (lane == 0) { red[wave] = L; red[8 + wave] = P; }
    __syncthreads();
    if (tid == 0) {
        float Ls = 0.f, Ps = 0.f;
        #pragma unroll
        for (int w = 0; w < 8; ++w) { Ls += red[w]; Ps += red[8 + w]; }
        out[0] = (Ls - Ps) * (1.0f / (float)N2);
    }
}

extern "C" void kernel_launch(void* const* d_in, const int* in_sizes, int n_in,
                              void* d_out, int out_size, void* d_ws, size_t ws_size,
                              hipStream_t stream) {
    const float*     zi = (const float*)d_in[0];
    const float*     zj = (const float*)d_in[1];
    const long long* y  = (const long long*)d_in[2];
    float* out = (float*)d_out;

    char* ws = (char*)d_ws;
    short* qb   = (short*)ws;                                  // 1 MB row-major
    short* qb2  = qb + N2 * D;                                 // 1 MB chunk-major
    float* pse  = (float*)(ws + 2 * N2 * D * sizeof(short));   // 4096*16 f32 = 256 KB
    float* S    = pse + N2 * NIT;                              // 1300 f32: S/T/CNT

    prep_kernel<<<N2, 64, 0, stream>>>(zi, zj, qb, qb2, S);
    main_kernel<<<GEMM_BLOCKS + CB, 512, 0, stream>>>(qb, qb2, y, pse, S);
    finish_kernel<<<1, 512, 0, stream>>>(pse, S, out);
}